// Round 4
// baseline (433.767 us; speedup 1.0000x reference)
//
#include <hip/hip_runtime.h>

// AdaConv2d: out[b,c,h,w] = sum_{ki,kj} xpad[b,c,h+ki-1,w+kj-1] * dk[b,c,ki*3+kj,h,w]
// x [8,64,128,128] f32, dk [8,64,9,128,128] f32, out [8,64,128,128] f32.
//
// R3 post-mortem: kernel ~120us vs 57us BW floor; ILP/nt changes were null.
// Theory: DRAM page thrash from ~10^4 concurrent short-lived 2KB tap-streams.
// Fix: block owns (bc, 32-row chunk); loops taps t=0..8 in ADDRESS ORDER,
// reading one contiguous 16KB chunk per tap (chunks ascend 64KB apart) ->
// each block streams its 144KB dk window sequentially. Thread owns 16 px
// (rows p and p+16 of the chunk, 8 cols); acc in regs; x preloaded (L1-hot).

constexpr int Bc = 8, Cc = 64, Hc = 128, Wc = 128;
constexpr int HW = Hc * Wc;
constexpr int ROWS = 32;              // rows per block chunk
constexpr int CHUNKS = Hc / ROWS;     // 4

typedef float f32x4 __attribute__((ext_vector_type(4)));

__device__ __forceinline__ void load_xrows(const float* __restrict__ xp,
                                           int R, int w0, float xr[3][10]) {
    #pragma unroll
    for (int r = 0; r < 3; ++r) {
        int hh = R + r - 1;
        if (hh >= 0 && hh < Hc) {
            const float* row = xp + hh * Wc;
            f32x4 m0 = *reinterpret_cast<const f32x4*>(row + w0);
            f32x4 m1 = *reinterpret_cast<const f32x4*>(row + w0 + 4);
            xr[r][1] = m0.x; xr[r][2] = m0.y; xr[r][3] = m0.z; xr[r][4] = m0.w;
            xr[r][5] = m1.x; xr[r][6] = m1.y; xr[r][7] = m1.z; xr[r][8] = m1.w;
            xr[r][0] = (w0 > 0)      ? row[w0 - 1] : 0.f;
            xr[r][9] = (w0 + 8 < Wc) ? row[w0 + 8] : 0.f;
        } else {
            #pragma unroll
            for (int q = 0; q < 10; ++q) xr[r][q] = 0.f;
        }
    }
}

__global__ __launch_bounds__(256) void adaconv2d_kernel(
    const float* __restrict__ x,
    const float* __restrict__ dk,
    float* __restrict__ out)
{
    int i  = threadIdx.x;
    int j  = i & 15;         // col-oct within row
    int p  = i >> 4;         // 0..15
    int w0 = j << 3;

    int blk = blockIdx.x;            // 0..2047
    int cb  = blk & (CHUNKS - 1);    // chunk within plane
    int bc  = blk >> 2;              // b*C + c

    int R0 = cb * ROWS + p;          // first owned absolute row
    int R1 = R0 + 16;                // second owned absolute row

    const float* xp = x + bc * HW;
    const float* kb = dk + (long long)bc * 9 * HW;

    // x neighborhoods for both owned rows (registers; L1-hot loads)
    float xa[3][10], xb[3][10];
    load_xrows(xp, R0, w0, xa);
    load_xrows(xp, R1, w0, xb);

    float a0[8], a1[8];
    #pragma unroll
    for (int q = 0; q < 8; ++q) { a0[q] = 0.f; a1[q] = 0.f; }

    #pragma unroll
    for (int t = 0; t < 9; ++t) {
        const int r = t / 3, s = t - 3 * r;
        const float* kt = kb + t * HW;
        f32x4 k0a = __builtin_nontemporal_load(reinterpret_cast<const f32x4*>(kt + R0 * Wc + w0));
        f32x4 k0b = __builtin_nontemporal_load(reinterpret_cast<const f32x4*>(kt + R0 * Wc + w0 + 4));
        f32x4 k1a = __builtin_nontemporal_load(reinterpret_cast<const f32x4*>(kt + R1 * Wc + w0));
        f32x4 k1b = __builtin_nontemporal_load(reinterpret_cast<const f32x4*>(kt + R1 * Wc + w0 + 4));

        // row R0, cols w0..w0+7  <- k0a (0..3), k0b (4..7)
        a0[0] += xa[r][s + 0] * k0a.x;
        a0[1] += xa[r][s + 1] * k0a.y;
        a0[2] += xa[r][s + 2] * k0a.z;
        a0[3] += xa[r][s + 3] * k0a.w;
        a0[4] += xa[r][s + 4] * k0b.x;
        a0[5] += xa[r][s + 5] * k0b.y;
        a0[6] += xa[r][s + 6] * k0b.z;
        a0[7] += xa[r][s + 7] * k0b.w;

        // row R1, cols w0..w0+7  <- k1a (0..3), k1b (4..7)
        a1[0] += xb[r][s + 0] * k1a.x;
        a1[1] += xb[r][s + 1] * k1a.y;
        a1[2] += xb[r][s + 2] * k1a.z;
        a1[3] += xb[r][s + 3] * k1a.w;
        a1[4] += xb[r][s + 4] * k1b.x;
        a1[5] += xb[r][s + 5] * k1b.y;
        a1[6] += xb[r][s + 6] * k1b.z;
        a1[7] += xb[r][s + 7] * k1b.w;
    }

    float* o0 = out + bc * HW + R0 * Wc + w0;
    float* o1 = out + bc * HW + R1 * Wc + w0;
    f32x4 s0a = { a0[0], a0[1], a0[2], a0[3] };
    f32x4 s0b = { a0[4], a0[5], a0[6], a0[7] };
    f32x4 s1a = { a1[0], a1[1], a1[2], a1[3] };
    f32x4 s1b = { a1[4], a1[5], a1[6], a1[7] };
    __builtin_nontemporal_store(s0a, reinterpret_cast<f32x4*>(o0));
    __builtin_nontemporal_store(s0b, reinterpret_cast<f32x4*>(o0 + 4));
    __builtin_nontemporal_store(s1a, reinterpret_cast<f32x4*>(o1));
    __builtin_nontemporal_store(s1b, reinterpret_cast<f32x4*>(o1 + 4));
}

extern "C" void kernel_launch(void* const* d_in, const int* in_sizes, int n_in,
                              void* d_out, int out_size, void* d_ws, size_t ws_size,
                              hipStream_t stream) {
    const float* x  = (const float*)d_in[0];
    const float* dk = (const float*)d_in[1];
    float* out      = (float*)d_out;

    const int grid = Bc * Cc * CHUNKS; // 2048 blocks
    adaconv2d_kernel<<<grid, 256, 0, stream>>>(x, dk, out);
}